// Round 8
// baseline (117.938 us; speedup 1.0000x reference)
//
#include <hip/hip_runtime.h>

#define B_TOT 8192
#define PP 32
#define QQ 32
#define RR 8
#define H1 128
#define H2 64
#define PHH 16
#define PAIRS 1024
#define OUT_UNITS 8192

#define NBLK_MM 256    // main-role: 128 btiles x 2 which, 512 thr (8 waves)
#define NBLK_IA 2048   // interact-role: 32 b-tiles of 256 x 64 pp-groups

typedef float f32x16 __attribute__((ext_vector_type(16)));
typedef float f32x2  __attribute__((ext_vector_type(2)));
typedef short s16x8  __attribute__((ext_vector_type(8)));

union FragU { s16x8 v; unsigned int u[4]; };
union DU    { f32x16 v; f32x2 p[8]; };

// RNE pack (v_cvt_pk_bf16_f32): low16 = bf16(lo), high16 = bf16(hi).
__device__ inline unsigned int pack_bf16(float lo, float hi) {
    unsigned int r;
    asm("v_cvt_pk_bf16_f32 %0, %1, %2" : "=v"(r) : "v"(lo), "v"(hi));
    return r;
}

// R16 = R15 + packed-f32 (VOP3P) arithmetic. CDNA4 runs v_pk_fma_f32 /
// v_pk_max_f32 at full rate (2 f32 lane-ops per inst). The IA hot loop's
// 72 scalar f32 VALU per body (h: 16 fma + 8 max; post: 16 add + 16 max +
// 16 fma) pair perfectly (weights are contiguous float4, d/acc contiguous
// f32x16) -> ~36 inst/body via <2 x float> elementwise builtins, saving
// ~288 inst/thread (~40% of hot loop). Same trick halves MM phase-A/B FMA
// streams. Bit-identical arithmetic -> absmax unchanged. If clang declines
// to pack, degrades to exactly the R15 stream.
union SharedU {
    union {
        struct {
            float zT[16][256];            // 16384 B
            float4 lwx[16][2];            // 512
            float4 lwz[16][2];            // 512
            float4 lhb[16][2];            // 512
            unsigned lpw1T[17][16][4];    // 4352 (entry p=16 = zeros)
            float lpbw[16][16][2];        // 2048 (pb1, pw2 interleaved)
        } s;                              // 24320 B
        float red[256][33];               // 33792 B (aliases staging after K-loop)
    } ia;
    struct {
        union {
            float xT[32][68];             // phase-A input (aliases h1T rows 0..31)
            float h1T[128][68];           // 34816 B; also reused as red[64][68]
        };
    } mm;
};

__global__ __launch_bounds__(512, 6) void fused_k(
    const float* __restrict__ x, const float* __restrict__ z,
    const float* __restrict__ xw1, const float* __restrict__ xb1,
    const float* __restrict__ xw2, const float* __restrict__ xb2,
    const float* __restrict__ xw3, const float* __restrict__ xb3,
    const float* __restrict__ zw1, const float* __restrict__ zb1,
    const float* __restrict__ zw2, const float* __restrict__ zb2,
    const float* __restrict__ zw3, const float* __restrict__ zb3,
    const float* __restrict__ xzw, const float* __restrict__ xzb,
    const float* __restrict__ pw1, const float* __restrict__ pb1,
    const float* __restrict__ pw2, float* __restrict__ out)
{
    __shared__ SharedU sh;
    const int bid  = blockIdx.x;
    const int t    = threadIdx.x;
    const int w    = t >> 6;
    const int lane = t & 63;
    const f32x2 zero2 = {0.f, 0.f};

    if (bid >= NBLK_MM) {
        // ------------------------- interaction role -------------------------
        const int ib    = bid - NBLK_MM;
        const int bx    = ib & 31;        // 32 b-tiles of 256
        const int y     = ib >> 5;        // 64 pp-groups
        const int m     = lane & 31;      // batch row within wave / C-D column
        const int kh    = lane >> 5;      // A k-half / pair selector
        const int jj    = m & 15;         // j within column's pair
        const int cph   = m >> 4;         // column's pair selector
        const int b0    = bx * 256;
        const int i_x   = y >> 1;
        const int k0    = (y & 1) * 16;
        const int pair0 = y * 16;

        // stage zT: 256 batches x 16 z-features (transposed)
        {
            int row = t >> 1;
            int c8  = (t & 1) * 8;
            const float* src = z + (size_t)(b0 + row) * 32 + k0 + c8;
            float4 a4 = *reinterpret_cast<const float4*>(src);
            float4 b4 = *reinterpret_cast<const float4*>(src + 4);
            sh.ia.s.zT[c8+0][row] = a4.x; sh.ia.s.zT[c8+1][row] = a4.y;
            sh.ia.s.zT[c8+2][row] = a4.z; sh.ia.s.zT[c8+3][row] = a4.w;
            sh.ia.s.zT[c8+4][row] = b4.x; sh.ia.s.zT[c8+5][row] = b4.y;
            sh.ia.s.zT[c8+6][row] = b4.z; sh.ia.s.zT[c8+7][row] = b4.w;
        }
        // stage h-layer weights (coalesced)
        if (t < 128) {
            int p = t >> 3, c = t & 7;
            int gp = pair0 + p;
            reinterpret_cast<float*>(sh.ia.s.lwx)[t] = xzw[(size_t)i_x * OUT_UNITS + gp*8 + c];
            reinterpret_cast<float*>(sh.ia.s.lwz)[t] = xzw[(size_t)(32 + k0 + p) * OUT_UNITS + gp*8 + c];
            reinterpret_cast<float*>(sh.ia.s.lhb)[t] = xzb[gp*8 + c];
        }
        // stage pb1 / pw2 interleaved (one ds_read_b64 in the hot loop)
        if (t < 256) {
            int p = t >> 4, j = t & 15;
            int gp = pair0 + p;
            float2 bw;
            bw.x = pb1[gp*PHH + j];
            bw.y = pw2[gp*PHH + j];
            *reinterpret_cast<float2*>(sh.ia.s.lpbw[p][j]) = bw;
        }
        // stage pw1 pre-packed bf16 (RNE), [p][j][u] layout for ds_read_b128
        // 16 rows x 16 j x 4 u = 1024 dwords -> it < 2 (complete for 16 rows)
        #pragma unroll
        for (int it = 0; it < 2; ++it) {
            int idx = t + it * 512;           // 1024 dwords
            int p = idx >> 6, u = (idx >> 4) & 3, j = idx & 15;
            int gp = pair0 + p;
            float lo = pw1[(size_t)gp * 128 + (2*u)*16 + j];
            float hi = pw1[(size_t)gp * 128 + (2*u+1)*16 + j];
            sh.ia.s.lpw1T[p][j][u] = pack_bf16(lo, hi);
        }
        if (t < 64) reinterpret_cast<unsigned*>(sh.ia.s.lpw1T[16])[t] = 0u;

        const int bl = w * 32 + m;            // this thread's batch row
        const float xv = x[(size_t)(b0 + bl) * 32 + i_x];
        __syncthreads();

        f32x2 acc2[8];
        #pragma unroll
        for (int r = 0; r < 8; ++r) acc2[r] = zero2;
        f32x16 zc;
        #pragma unroll
        for (int r = 0; r < 16; ++r) zc[r] = 0.f;

        const bool realB = (kh == cph);
        const f32x2 xvv = {xv, xv};

        #pragma unroll 2
        for (int ppl = 0; ppl < 8; ++ppl) {
            const int pAl = 2*ppl + kh;
            const int pBl = 2*ppl + cph;

            const float zv = sh.ia.s.zT[pAl][bl];
            const f32x2 zvv = {zv, zv};
            const f32x2* wx2 = reinterpret_cast<const f32x2*>(&sh.ia.s.lwx[pAl][0]);
            const f32x2* wz2 = reinterpret_cast<const f32x2*>(&sh.ia.s.lwz[pAl][0]);
            const f32x2* hb2 = reinterpret_cast<const f32x2*>(&sh.ia.s.lhb[pAl][0]);

            // h = max(x*wx + (z*wz + b), 0) — packed 2-wide: 3 VOP3P per quad
            f32x2 h2[4];
            #pragma unroll
            for (int q = 0; q < 4; ++q) {
                f32x2 tt = __builtin_elementwise_fma(zvv, wz2[q], hb2[q]);
                tt = __builtin_elementwise_fma(xvv, wx2[q], tt);
                h2[q] = __builtin_elementwise_max(tt, zero2);
            }

            FragU a0, bf;
            a0.u[0] = pack_bf16(h2[0][0], h2[0][1]);
            a0.u[1] = pack_bf16(h2[1][0], h2[1][1]);
            a0.u[2] = pack_bf16(h2[2][0], h2[2][1]);
            a0.u[3] = pack_bf16(h2[3][0], h2[3][1]);

            // B-frag: one index cndmask + ds_read_b128 (zeros at p=16)
            const unsigned* bq = sh.ia.s.lpw1T[realB ? pBl : 16][jj];
            bf.u[0] = bq[0]; bf.u[1] = bq[1]; bf.u[2] = bq[2]; bf.u[3] = bq[3];

            const float2 bw = *reinterpret_cast<const float2*>(sh.ia.s.lpbw[pBl][jj]);
            const f32x2 bx2 = {bw.x, bw.x};
            const f32x2 by2 = {bw.y, bw.y};

            // zero-C MFMA; bias added post-MFMA (packed)
            DU du;
            du.v = __builtin_amdgcn_mfma_f32_32x32x16_bf16(a0.v, bf.v, zc, 0, 0, 0);

            #pragma unroll
            for (int r = 0; r < 8; ++r) {
                f32x2 tt = __builtin_elementwise_max(du.p[r] + bx2, zero2);
                acc2[r] = __builtin_elementwise_fma(tt, by2, acc2[r]);
            }
        }

        __syncthreads();   // staging LDS dead; red aliases it from here on
        #pragma unroll
        for (int r = 0; r < 16; ++r) {
            int rowf = (r & 3) + 8 * (r >> 2) + 4 * kh;
            sh.ia.red[w * 32 + rowf][m] = acc2[r >> 1][r & 1];
        }
        __syncthreads();
        {   // all 512 threads: half-row sums + pair shuffle, 256 atomics
            int row = t >> 1, hh = t & 1;
            const float* rr = &sh.ia.red[row][hh * 16];
            float ssum = 0.f;
            #pragma unroll
            for (int c = 0; c < 16; ++c) ssum += rr[c];
            ssum += __shfl_xor(ssum, 1);
            if (hh == 0) atomicAdd(out + b0 + row, ssum);
        }
    } else {
        // --------------------------- main-MLP role ---------------------------
        // lane = neuron, wave = 8 batches; all weight loads per-lane coalesced.
        const int btile = bid & 127;
        const int which = bid >> 7;
        const float* in = which ? z   : x;
        const float* w1 = which ? zw1 : xw1;
        const float* b1 = which ? zb1 : xb1;
        const float* w2 = which ? zw2 : xw2;
        const float* b2 = which ? zb2 : xb2;
        const float* w3 = which ? zw3 : xw3;
        const float* b3 = which ? zb3 : xb3;
        const int b0 = btile * 64;
        const int bw = w * 8;            // this wave's local batch base

        // stage xT[32][68] transposed (aliases h1T rows 0..31)
        {
            int row = t >> 3;            // batch 0..63
            int c4  = (t & 7) * 4;       // feature 0..28 step 4
            float4 v = *reinterpret_cast<const float4*>(in + (size_t)(b0 + row) * 32 + c4);
            sh.mm.xT[c4+0][row] = v.x; sh.mm.xT[c4+1][row] = v.y;
            sh.mm.xT[c4+2][row] = v.z; sh.mm.xT[c4+3][row] = v.w;
        }
        __syncthreads();

        // phase A: h1 for neurons j=lane and lane+64, batches [bw, bw+8)
        const int j1 = lane, j2 = lane + 64;
        f32x2 a1p[4], a2p[4];
        {
            float bb1 = b1[j1], bb2 = b1[j2];
            f32x2 b1v = {bb1, bb1}, b2v = {bb2, bb2};
            #pragma unroll
            for (int i = 0; i < 4; ++i) { a1p[i] = b1v; a2p[i] = b2v; }
        }
        #pragma unroll 4
        for (int m = 0; m < 32; ++m) {
            const f32x2* xp = reinterpret_cast<const f32x2*>(&sh.mm.xT[m][bw]);
            float wv1 = w1[m*H1 + j1];
            float wv2 = w1[m*H1 + j2];
            f32x2 w1v = {wv1, wv1}, w2v = {wv2, wv2};
            #pragma unroll
            for (int q = 0; q < 4; ++q) {
                f32x2 xq = xp[q];
                a1p[q] = __builtin_elementwise_fma(xq, w1v, a1p[q]);
                a2p[q] = __builtin_elementwise_fma(xq, w2v, a2p[q]);
            }
        }
        __syncthreads();          // all xT reads done (h1T writes alias xT)
        #pragma unroll
        for (int q = 0; q < 4; ++q) {
            f32x2 r1 = __builtin_elementwise_max(a1p[q], zero2);
            f32x2 r2 = __builtin_elementwise_max(a2p[q], zero2);
            sh.mm.h1T[j1][bw + 2*q + 0] = r1[0];
            sh.mm.h1T[j1][bw + 2*q + 1] = r1[1];
            sh.mm.h1T[j2][bw + 2*q + 0] = r2[0];
            sh.mm.h1T[j2][bw + 2*q + 1] = r2[1];
        }
        __syncthreads();

        // phase B: h2 for neuron n=lane, batches [bw, bw+8)
        f32x2 hp[4];
        {
            float b2v = b2[lane];
            f32x2 bb = {b2v, b2v};
            #pragma unroll
            for (int i = 0; i < 4; ++i) hp[i] = bb;
        }
        #pragma unroll 4
        for (int m = 0; m < 128; ++m) {
            float w2v = w2[m*H2 + lane];
            f32x2 wv = {w2v, w2v};
            const f32x2* hr = reinterpret_cast<const f32x2*>(&sh.mm.h1T[m][bw]);
            #pragma unroll
            for (int q = 0; q < 4; ++q)
                hp[q] = __builtin_elementwise_fma(hr[q], wv, hp[q]);
        }
        float hacc[8];
        {
            float w3v = w3[lane];
            #pragma unroll
            for (int q = 0; q < 4; ++q) {
                f32x2 r = __builtin_elementwise_max(hp[q], zero2);
                hacc[2*q+0] = r[0] * w3v;
                hacc[2*q+1] = r[1] * w3v;
            }
        }
        __syncthreads();          // phase-B h1T reads done (red aliases h1T)
        #pragma unroll
        for (int i = 0; i < 8; ++i)
            sh.mm.h1T[bw + i][lane] = hacc[i];   // red[b][n]
        __syncthreads();
        if (t < 64) {
            float s = b3[0];
            const float4* rr = reinterpret_cast<const float4*>(&sh.mm.h1T[t][0]);
            #pragma unroll
            for (int c = 0; c < 16; ++c) {
                float4 v = rr[c];
                s += (v.x + v.y) + (v.z + v.w);
            }
            atomicAdd(out + b0 + t, s);
        }
    }
}

extern "C" void kernel_launch(void* const* d_in, const int* in_sizes, int n_in,
                              void* d_out, int out_size, void* d_ws, size_t ws_size,
                              hipStream_t stream) {
    const float* x   = (const float*)d_in[0];
    const float* z   = (const float*)d_in[1];
    const float* xw1 = (const float*)d_in[2];
    const float* xb1 = (const float*)d_in[3];
    const float* xw2 = (const float*)d_in[4];
    const float* xb2 = (const float*)d_in[5];
    const float* xw3 = (const float*)d_in[6];
    const float* xb3 = (const float*)d_in[7];
    const float* zw1 = (const float*)d_in[8];
    const float* zb1 = (const float*)d_in[9];
    const float* zw2 = (const float*)d_in[10];
    const float* zb2 = (const float*)d_in[11];
    const float* zw3 = (const float*)d_in[12];
    const float* zb3 = (const float*)d_in[13];
    const float* xzw = (const float*)d_in[14];
    const float* xzb = (const float*)d_in[15];
    const float* pw1 = (const float*)d_in[16];
    const float* pb1 = (const float*)d_in[17];
    const float* pw2 = (const float*)d_in[18];
    float* out = (float*)d_out;

    hipMemsetAsync(out, 0, (size_t)out_size * sizeof(float), stream);

    fused_k<<<dim3(NBLK_MM + NBLK_IA), 512, 0, stream>>>(
        x, z, xw1, xb1, xw2, xb2, xw3, xb3,
        zw1, zb1, zw2, zb2, zw3, zb3,
        xzw, xzb, pw1, pb1, pw2, out);
}

// Round 11
// 116.058 us; speedup vs baseline: 1.0162x; 1.0162x over previous
//
#include <hip/hip_runtime.h>

#define B_TOT 8192
#define PP 32
#define QQ 32
#define RR 8
#define H1 128
#define H2 64
#define PHH 16
#define PAIRS 1024
#define OUT_UNITS 8192

#define NBLK_MM 512    // main-role: 256 btiles(32 batches) x 2 which, 256 thr
#define NBLK_IA 4096   // interact-role: 64 b-tiles of 128 x 64 pp-groups, 256 thr

typedef float f32x16 __attribute__((ext_vector_type(16)));
typedef float f32x2  __attribute__((ext_vector_type(2)));
typedef short s16x8  __attribute__((ext_vector_type(8)));

union FragU { s16x8 v; unsigned int u[4]; };
union DU    { f32x16 v; f32x2 p[8]; };

// RNE pack (v_cvt_pk_bf16_f32): low16 = bf16(lo), high16 = bf16(hi).
__device__ inline unsigned int pack_bf16(float lo, float hi) {
    unsigned int r;
    asm("v_cvt_pk_bf16_f32 %0, %1, %2" : "=v"(r) : "v"(lo), "v"(hi));
    return r;
}

// R18 (resubmitted after broker timeout; never ran). R17's MM-role bug:
// h1T narrowed to [128][36] but the final reduction still wrote
// red[b][lane] with lane<64 into 36-wide rows (out-of-row wrap ->
// absmax 1.15). Fix: dedicated red[32][68] member aliasing the dead h1T
// space. Occupancy experiment unchanged: 256-thr blocks, 8 wg/CU
// (= 32 waves, 100% thread cap), half-width barriers. R8's null result
// (packed math, -30% issue, 0 gain) proved latency-bound; residency is
// the remaining lever. Tripwire: WRITE_SIZE (spill).
union SharedU {
    union {
        struct {
            float zT[16][128];            // 8192 B (128-batch tile)
            float4 lwx[16][2];            // 512
            float4 lwz[16][2];            // 512
            float4 lhb[16][2];            // 512
            unsigned lpw1T[17][16][4];    // 4352 (entry p=16 = zeros)
            float lpbw[16][16][2];        // 2048 (pb1, pw2 interleaved)
        } s;                              // 16128 B
        float red[128][33];               // 16896 B (aliases staging after K-loop)
    } ia;
    union {
        struct {
            union {
                float xT[32][36];         // phase-A input (aliases h1T rows 0..31)
                float h1T[128][36];       // 18432 B
            };
        };
        float red[32][68];                // 8704 B (aliases h1T after phase B)
    } mm;
};

__global__ __launch_bounds__(256, 8) void fused_k(
    const float* __restrict__ x, const float* __restrict__ z,
    const float* __restrict__ xw1, const float* __restrict__ xb1,
    const float* __restrict__ xw2, const float* __restrict__ xb2,
    const float* __restrict__ xw3, const float* __restrict__ xb3,
    const float* __restrict__ zw1, const float* __restrict__ zb1,
    const float* __restrict__ zw2, const float* __restrict__ zb2,
    const float* __restrict__ zw3, const float* __restrict__ zb3,
    const float* __restrict__ xzw, const float* __restrict__ xzb,
    const float* __restrict__ pw1, const float* __restrict__ pb1,
    const float* __restrict__ pw2, float* __restrict__ out)
{
    __shared__ SharedU sh;
    const int bid  = blockIdx.x;
    const int t    = threadIdx.x;
    const int w    = t >> 6;            // 0..3
    const int lane = t & 63;
    const f32x2 zero2 = {0.f, 0.f};

    if (bid >= NBLK_MM) {
        // ------------------------- interaction role -------------------------
        const int ib    = bid - NBLK_MM;
        const int bx    = ib & 63;        // 64 b-tiles of 128
        const int y     = ib >> 6;        // 64 pp-groups
        const int m     = lane & 31;      // batch row within wave / C-D column
        const int kh    = lane >> 5;      // A k-half / pair selector
        const int jj    = m & 15;         // j within column's pair
        const int cph   = m >> 4;         // column's pair selector
        const int b0    = bx * 128;
        const int i_x   = y >> 1;
        const int k0    = (y & 1) * 16;
        const int pair0 = y * 16;

        // stage zT: 128 batches x 16 z-features (transposed)
        {
            int row = t >> 1;             // 0..127
            int c8  = (t & 1) * 8;
            const float* src = z + (size_t)(b0 + row) * 32 + k0 + c8;
            float4 a4 = *reinterpret_cast<const float4*>(src);
            float4 b4 = *reinterpret_cast<const float4*>(src + 4);
            sh.ia.s.zT[c8+0][row] = a4.x; sh.ia.s.zT[c8+1][row] = a4.y;
            sh.ia.s.zT[c8+2][row] = a4.z; sh.ia.s.zT[c8+3][row] = a4.w;
            sh.ia.s.zT[c8+4][row] = b4.x; sh.ia.s.zT[c8+5][row] = b4.y;
            sh.ia.s.zT[c8+6][row] = b4.z; sh.ia.s.zT[c8+7][row] = b4.w;
        }
        // stage h-layer weights (coalesced)
        if (t < 128) {
            int p = t >> 3, c = t & 7;
            int gp = pair0 + p;
            reinterpret_cast<float*>(sh.ia.s.lwx)[t] = xzw[(size_t)i_x * OUT_UNITS + gp*8 + c];
            reinterpret_cast<float*>(sh.ia.s.lwz)[t] = xzw[(size_t)(32 + k0 + p) * OUT_UNITS + gp*8 + c];
            reinterpret_cast<float*>(sh.ia.s.lhb)[t] = xzb[gp*8 + c];
        }
        // stage pb1 / pw2 interleaved (256 entries = all threads)
        {
            int p = t >> 4, j = t & 15;
            int gp = pair0 + p;
            float2 bw;
            bw.x = pb1[gp*PHH + j];
            bw.y = pw2[gp*PHH + j];
            *reinterpret_cast<float2*>(sh.ia.s.lpbw[p][j]) = bw;
        }
        // stage pw1 pre-packed bf16 (RNE), [p][j][u] layout for ds_read_b128
        // 16 rows x 16 j x 4 u = 1024 dwords -> 4 iters of 256 threads
        #pragma unroll
        for (int it = 0; it < 4; ++it) {
            int idx = t + it * 256;           // 1024 dwords
            int p = idx >> 6, u = (idx >> 4) & 3, j = idx & 15;
            int gp = pair0 + p;
            float lo = pw1[(size_t)gp * 128 + (2*u)*16 + j];
            float hi = pw1[(size_t)gp * 128 + (2*u+1)*16 + j];
            sh.ia.s.lpw1T[p][j][u] = pack_bf16(lo, hi);
        }
        if (t < 64) reinterpret_cast<unsigned*>(sh.ia.s.lpw1T[16])[t] = 0u;

        const int bl = w * 32 + m;            // this thread's batch row (0..127)
        const float xv = x[(size_t)(b0 + bl) * 32 + i_x];
        __syncthreads();

        f32x2 acc2[8];
        #pragma unroll
        for (int r = 0; r < 8; ++r) acc2[r] = zero2;
        f32x16 zc;
        #pragma unroll
        for (int r = 0; r < 16; ++r) zc[r] = 0.f;

        const bool realB = (kh == cph);
        const f32x2 xvv = {xv, xv};

        #pragma unroll 2
        for (int ppl = 0; ppl < 8; ++ppl) {
            const int pAl = 2*ppl + kh;
            const int pBl = 2*ppl + cph;

            const float zv = sh.ia.s.zT[pAl][bl];
            const f32x2 zvv = {zv, zv};
            const f32x2* wx2 = reinterpret_cast<const f32x2*>(&sh.ia.s.lwx[pAl][0]);
            const f32x2* wz2 = reinterpret_cast<const f32x2*>(&sh.ia.s.lwz[pAl][0]);
            const f32x2* hb2 = reinterpret_cast<const f32x2*>(&sh.ia.s.lhb[pAl][0]);

            // h = max(x*wx + (z*wz + b), 0) — packed 2-wide
            f32x2 h2[4];
            #pragma unroll
            for (int q = 0; q < 4; ++q) {
                f32x2 tt = __builtin_elementwise_fma(zvv, wz2[q], hb2[q]);
                tt = __builtin_elementwise_fma(xvv, wx2[q], tt);
                h2[q] = __builtin_elementwise_max(tt, zero2);
            }

            FragU a0, bf;
            a0.u[0] = pack_bf16(h2[0][0], h2[0][1]);
            a0.u[1] = pack_bf16(h2[1][0], h2[1][1]);
            a0.u[2] = pack_bf16(h2[2][0], h2[2][1]);
            a0.u[3] = pack_bf16(h2[3][0], h2[3][1]);

            // B-frag: one index cndmask + ds_read_b128 (zeros at p=16)
            const unsigned* bq = sh.ia.s.lpw1T[realB ? pBl : 16][jj];
            bf.u[0] = bq[0]; bf.u[1] = bq[1]; bf.u[2] = bq[2]; bf.u[3] = bq[3];

            const float2 bw = *reinterpret_cast<const float2*>(sh.ia.s.lpbw[pBl][jj]);
            const f32x2 bx2 = {bw.x, bw.x};
            const f32x2 by2 = {bw.y, bw.y};

            // zero-C MFMA; bias added post-MFMA (packed)
            DU du;
            du.v = __builtin_amdgcn_mfma_f32_32x32x16_bf16(a0.v, bf.v, zc, 0, 0, 0);

            #pragma unroll
            for (int r = 0; r < 8; ++r) {
                f32x2 tt = __builtin_elementwise_max(du.p[r] + bx2, zero2);
                acc2[r] = __builtin_elementwise_fma(tt, by2, acc2[r]);
            }
        }

        __syncthreads();   // staging LDS dead; red aliases it from here on
        #pragma unroll
        for (int r = 0; r < 16; ++r) {
            int rowf = (r & 3) + 8 * (r >> 2) + 4 * kh;
            sh.ia.red[w * 32 + rowf][m] = acc2[r >> 1][r & 1];
        }
        __syncthreads();
        {   // all 256 threads: half-row sums + pair shuffle, 128 atomics
            int row = t >> 1, hh = t & 1;
            const float* rr = &sh.ia.red[row][hh * 16];
            float ssum = 0.f;
            #pragma unroll
            for (int c = 0; c < 16; ++c) ssum += rr[c];
            ssum += __shfl_xor(ssum, 1);
            if (hh == 0) atomicAdd(out + b0 + row, ssum);
        }
    } else {
        // --------------------------- main-MLP role ---------------------------
        // 256 threads, 32-batch tile; lane = neuron, wave = 8 batches.
        const int btile = bid & 255;
        const int which = bid >> 8;
        const float* in = which ? z   : x;
        const float* w1 = which ? zw1 : xw1;
        const float* b1 = which ? zb1 : xb1;
        const float* w2 = which ? zw2 : xw2;
        const float* b2 = which ? zb2 : xb2;
        const float* w3 = which ? zw3 : xw3;
        const float* b3 = which ? zb3 : xb3;
        const int b0 = btile * 32;
        const int bw = w * 8;            // this wave's local batch base (0..24)

        // stage xT[32][36] transposed (aliases h1T rows 0..31)
        {
            int row = t >> 3;            // batch 0..31
            int c4  = (t & 7) * 4;       // feature 0..28 step 4
            float4 v = *reinterpret_cast<const float4*>(in + (size_t)(b0 + row) * 32 + c4);
            sh.mm.xT[c4+0][row] = v.x; sh.mm.xT[c4+1][row] = v.y;
            sh.mm.xT[c4+2][row] = v.z; sh.mm.xT[c4+3][row] = v.w;
        }
        __syncthreads();

        // phase A: h1 for neurons j=lane and lane+64, batches [bw, bw+8)
        const int j1 = lane, j2 = lane + 64;
        f32x2 a1p[4], a2p[4];
        {
            float bb1 = b1[j1], bb2 = b1[j2];
            f32x2 b1v = {bb1, bb1}, b2v = {bb2, bb2};
            #pragma unroll
            for (int i = 0; i < 4; ++i) { a1p[i] = b1v; a2p[i] = b2v; }
        }
        #pragma unroll 4
        for (int m = 0; m < 32; ++m) {
            const f32x2* xp = reinterpret_cast<const f32x2*>(&sh.mm.xT[m][bw]);
            float wv1 = w1[m*H1 + j1];
            float wv2 = w1[m*H1 + j2];
            f32x2 w1v = {wv1, wv1}, w2v = {wv2, wv2};
            #pragma unroll
            for (int q = 0; q < 4; ++q) {
                f32x2 xq = xp[q];
                a1p[q] = __builtin_elementwise_fma(xq, w1v, a1p[q]);
                a2p[q] = __builtin_elementwise_fma(xq, w2v, a2p[q]);
            }
        }
        __syncthreads();          // all xT reads done (h1T writes alias xT)
        #pragma unroll
        for (int q = 0; q < 4; ++q) {
            f32x2 r1 = __builtin_elementwise_max(a1p[q], zero2);
            f32x2 r2 = __builtin_elementwise_max(a2p[q], zero2);
            sh.mm.h1T[j1][bw + 2*q + 0] = r1[0];
            sh.mm.h1T[j1][bw + 2*q + 1] = r1[1];
            sh.mm.h1T[j2][bw + 2*q + 0] = r2[0];
            sh.mm.h1T[j2][bw + 2*q + 1] = r2[1];
        }
        __syncthreads();

        // phase B: h2 for neuron n=lane, batches [bw, bw+8)
        f32x2 hp[4];
        {
            float b2v = b2[lane];
            f32x2 bb = {b2v, b2v};
            #pragma unroll
            for (int i = 0; i < 4; ++i) hp[i] = bb;
        }
        #pragma unroll 4
        for (int m = 0; m < 128; ++m) {
            float w2v = w2[m*H2 + lane];
            f32x2 wv = {w2v, w2v};
            const f32x2* hr = reinterpret_cast<const f32x2*>(&sh.mm.h1T[m][bw]);
            #pragma unroll
            for (int q = 0; q < 4; ++q)
                hp[q] = __builtin_elementwise_fma(hr[q], wv, hp[q]);
        }
        float hacc[8];
        {
            float w3v = w3[lane];
            #pragma unroll
            for (int q = 0; q < 4; ++q) {
                f32x2 r = __builtin_elementwise_max(hp[q], zero2);
                hacc[2*q+0] = r[0] * w3v;
                hacc[2*q+1] = r[1] * w3v;
            }
        }
        __syncthreads();          // phase-B h1T reads done (red aliases h1T)
        #pragma unroll
        for (int i = 0; i < 8; ++i)
            sh.mm.red[bw + i][lane] = hacc[i];   // red[b][n], 32 x 64 used
        __syncthreads();
        if (t < 32) {
            float s = b3[0];
            const float4* rr = reinterpret_cast<const float4*>(&sh.mm.red[t][0]);
            #pragma unroll
            for (int c = 0; c < 16; ++c) {
                float4 v = rr[c];
                s += (v.x + v.y) + (v.z + v.w);
            }
            atomicAdd(out + b0 + t, s);
        }
    }
}

extern "C" void kernel_launch(void* const* d_in, const int* in_sizes, int n_in,
                              void* d_out, int out_size, void* d_ws, size_t ws_size,
                              hipStream_t stream) {
    const float* x   = (const float*)d_in[0];
    const float* z   = (const float*)d_in[1];
    const float* xw1 = (const float*)d_in[2];
    const float* xb1 = (const float*)d_in[3];
    const float* xw2 = (const float*)d_in[4];
    const float* xb2 = (const float*)d_in[5];
    const float* xw3 = (const float*)d_in[6];
    const float* xb3 = (const float*)d_in[7];
    const float* zw1 = (const float*)d_in[8];
    const float* zb1 = (const float*)d_in[9];
    const float* zw2 = (const float*)d_in[10];
    const float* zb2 = (const float*)d_in[11];
    const float* zw3 = (const float*)d_in[12];
    const float* zb3 = (const float*)d_in[13];
    const float* xzw = (const float*)d_in[14];
    const float* xzb = (const float*)d_in[15];
    const float* pw1 = (const float*)d_in[16];
    const float* pb1 = (const float*)d_in[17];
    const float* pw2 = (const float*)d_in[18];
    float* out = (float*)d_out;

    hipMemsetAsync(out, 0, (size_t)out_size * sizeof(float), stream);

    fused_k<<<dim3(NBLK_MM + NBLK_IA), 256, 0, stream>>>(
        x, z, xw1, xb1, xw2, xb2, xw3, xb3,
        zw1, zb1, zw2, zb2, zw3, zb3,
        xzw, xzb, pw1, pb1, pw2, out);
}